// Round 1
// baseline (413.652 us; speedup 1.0000x reference)
//
#include <hip/hip_runtime.h>
#include <hip/hip_bf16.h>

typedef __attribute__((ext_vector_type(8))) short short8;
typedef __attribute__((ext_vector_type(4))) float f32x4;
typedef unsigned short u16;

// Problem constants (B=4, S=8192, D=1024, H=16, d=64, bs=64)
#define M_TOK   32768      // B*S
#define DIM     1024
#define NHEAD   16
#define HDIM    64
#define NBLK    128        // S / 64

__device__ __forceinline__ u16 f2b(float f) {
  union { float f; unsigned u; } v; v.f = f;
  unsigned r = (v.u + 0x7FFFu + ((v.u >> 16) & 1u)) >> 16;
  return (u16)r;
}

// ---------------- convert x fp32 -> bf16 (row-major, unchanged layout) -------
__global__ void cvt_x_kernel(const float* __restrict__ in, u16* __restrict__ out, int n8) {
  int i = blockIdx.x * 256 + threadIdx.x;
  if (i >= n8) return;
  const float4* p = (const float4*)in + (size_t)i * 2;
  float4 a = p[0], c = p[1];
  short8 o;
  o[0] = (short)f2b(a.x); o[1] = (short)f2b(a.y); o[2] = (short)f2b(a.z); o[3] = (short)f2b(a.w);
  o[4] = (short)f2b(c.x); o[5] = (short)f2b(c.y); o[6] = (short)f2b(c.z); o[7] = (short)f2b(c.w);
  *((short8*)out + i) = o;
}

// ------------- convert W (K,N) fp32 -> W^T (N,K) bf16, 3 matrices -----------
// thread t -> (mat, kgroup of 8, n). Reads coalesced along n, writes 16B.
__global__ void cvt_wT_kernel(const float* __restrict__ Wq, const float* __restrict__ Wk,
                              const float* __restrict__ Wv, u16* __restrict__ wT) {
  int t = blockIdx.x * 256 + threadIdx.x;   // 3*128*1024 = 393216 threads
  int mat = t >> 17;
  int rem = t & 131071;
  int kg  = rem >> 10;       // 0..127
  int n   = rem & 1023;
  const float* W = (mat == 0) ? Wq : (mat == 1) ? Wk : Wv;
  short8 v;
  #pragma unroll
  for (int i = 0; i < 8; ++i) v[i] = (short)f2b(W[(size_t)(kg * 8 + i) * DIM + n]);
  *(short8*)(wT + ((size_t)mat << 20) + (size_t)n * DIM + kg * 8) = v;
}

// ---------------- QKV projection GEMM: C = x @ W + b, bf16 MFMA --------------
// 128x128 tile, BK=64, 4 waves (2x2), per-wave 4x4 of 16x16x32 MFMA (m97 structure)
__global__ __launch_bounds__(256) void qkv_gemm_kernel(
    const u16* __restrict__ xb, const u16* __restrict__ wT,
    const float* __restrict__ bq, const float* __restrict__ bk, const float* __restrict__ bv,
    u16* __restrict__ qb, u16* __restrict__ kb, u16* __restrict__ vb)
{
  __shared__ u16 As[128 * 64];   // [row][k]
  __shared__ u16 Bs[128 * 64];   // [n][k]  (W^T tile)
  const int tid  = threadIdx.x;
  const int lane = tid & 63;
  const int wid  = tid >> 6;
  const int bm   = blockIdx.x;          // 0..255
  const int bn   = blockIdx.y;          // 0..23
  const int mat  = bn >> 3;             // 0=q 1=k 2=v
  const int col0 = (bn & 7) << 7;
  const int row0 = bm << 7;
  const u16* Wm = wT + ((size_t)mat << 20);
  const float* bias = (mat == 0) ? bq : (mat == 1) ? bk : bv;
  u16* outp = (mat == 0) ? qb : (mat == 1) ? kb : vb;

  const int wr = (wid >> 1) << 6;       // wave row offset in tile
  const int wc = (wid & 1) << 6;        // wave col offset

  f32x4 acc[4][4] = {};

  const int lr = lane >> 3;             // 0..7
  const int lc = (lane & 7) << 3;       // 0..56 (elems)
  // per-lane global bases for chunk (c*4 + wid): rows chunk*8 + lr
  const u16* agp = xb + (size_t)(row0 + wid * 8 + lr) * DIM + lc;
  const u16* bgp = Wm + (size_t)(col0 + wid * 8 + lr) * DIM + lc;

  for (int kt = 0; kt < 1024; kt += 64) {
    #pragma unroll
    for (int c = 0; c < 4; ++c) {
      int chunk = (c << 2) + wid;       // 16 chunks of 1KB each per buffer
      __builtin_amdgcn_global_load_lds(
          (const __attribute__((address_space(1))) void*)(agp + (size_t)c * 32 * DIM + kt),
          (__attribute__((address_space(3))) void*)(As + chunk * 512), 16, 0, 0);
      __builtin_amdgcn_global_load_lds(
          (const __attribute__((address_space(1))) void*)(bgp + (size_t)c * 32 * DIM + kt),
          (__attribute__((address_space(3))) void*)(Bs + chunk * 512), 16, 0, 0);
    }
    __syncthreads();   // compiler drains vmcnt before barrier
    #pragma unroll
    for (int kk = 0; kk < 2; ++kk) {
      short8 a[4], bb[4];
      #pragma unroll
      for (int mi = 0; mi < 4; ++mi)
        a[mi] = *(const short8*)(As + (wr + mi * 16 + (lane & 15)) * 64 + kk * 32 + ((lane >> 4) << 3));
      #pragma unroll
      for (int ni = 0; ni < 4; ++ni)
        bb[ni] = *(const short8*)(Bs + (wc + ni * 16 + (lane & 15)) * 64 + kk * 32 + ((lane >> 4) << 3));
      #pragma unroll
      for (int mi = 0; mi < 4; ++mi)
        #pragma unroll
        for (int ni = 0; ni < 4; ++ni)
          acc[mi][ni] = __builtin_amdgcn_mfma_f32_16x16x32_bf16(a[mi], bb[ni], acc[mi][ni], 0, 0, 0);
    }
    __syncthreads();
  }

  // epilogue: bias + bf16 store. C/D layout: col = lane&15, row = (lane>>4)*4 + r
  #pragma unroll
  for (int ni = 0; ni < 4; ++ni) {
    int gcol = col0 + wc + ni * 16 + (lane & 15);
    float bv_ = bias[gcol];
    #pragma unroll
    for (int mi = 0; mi < 4; ++mi) {
      int grow = row0 + wr + mi * 16 + ((lane >> 4) << 2);
      #pragma unroll
      for (int r = 0; r < 4; ++r)
        outp[(size_t)(grow + r) * DIM + gcol] = f2b(acc[mi][ni][r] + bv_);
    }
  }
}

// ---------------- block-diagonal attention: one WG per (b, blk, h) -----------
// 4 waves; wave w owns query rows [16w, 16w+16) of the 64x64 tile.
__global__ __launch_bounds__(256) void blk_attn_kernel(
    const u16* __restrict__ qb, const u16* __restrict__ kb, const u16* __restrict__ vb,
    float* __restrict__ out)
{
  __shared__ u16 qs[64 * 72];    // [i][d]   stride 72 (144B, 16B-aligned rows)
  __shared__ u16 ks[64 * 72];    // [j][d]
  __shared__ u16 vts[64 * 72];   // [d][j]  (v transposed)
  __shared__ u16 ps[64 * 72];    // [i][j]  P in bf16

  const int tid  = threadIdx.x;
  const int lane = tid & 63;
  const int wid  = tid >> 6;
  const int idx  = blockIdx.x;        // B * NBLK * NHEAD = 8192
  const int h    = idx & 15;
  const int blk  = (idx >> 4) & 127;
  const int b    = idx >> 11;
  const size_t s0 = (size_t)b * 8192 + (size_t)blk * 64;   // global token row
  const int h0 = h * HDIM;

  // stage q, k, v (v transposed) into LDS
  {
    int i  = tid >> 2;              // 0..63
    int cg = (tid & 3) * 16;        // 0,16,32,48
    const u16* qg = qb + (s0 + i) * DIM + h0 + cg;
    *(short8*)(qs + i * 72 + cg)     = *(const short8*)qg;
    *(short8*)(qs + i * 72 + cg + 8) = *(const short8*)(qg + 8);
    const u16* kg = kb + (s0 + i) * DIM + h0 + cg;
    *(short8*)(ks + i * 72 + cg)     = *(const short8*)kg;
    *(short8*)(ks + i * 72 + cg + 8) = *(const short8*)(kg + 8);
    const u16* vg = vb + (s0 + i) * DIM + h0 + cg;
    short8 v0 = *(const short8*)vg;
    short8 v1 = *(const short8*)(vg + 8);
    #pragma unroll
    for (int e = 0; e < 8; ++e) {
      vts[(cg + e) * 72 + i]     = (u16)v0[e];
      vts[(cg + 8 + e) * 72 + i] = (u16)v1[e];
    }
  }
  __syncthreads();

  // S = q @ k^T  (M=16 rows for this wave, N=64, K=64)
  f32x4 S[4] = {};
  {
    short8 aq[2];
    #pragma unroll
    for (int kk = 0; kk < 2; ++kk)
      aq[kk] = *(const short8*)(qs + (wid * 16 + (lane & 15)) * 72 + kk * 32 + ((lane >> 4) << 3));
    #pragma unroll
    for (int jt = 0; jt < 4; ++jt)
      #pragma unroll
      for (int kk = 0; kk < 2; ++kk) {
        short8 bk_ = *(const short8*)(ks + (jt * 16 + (lane & 15)) * 72 + kk * 32 + ((lane >> 4) << 3));
        S[jt] = __builtin_amdgcn_mfma_f32_16x16x32_bf16(aq[kk], bk_, S[jt], 0, 0, 0);
      }
  }

  // softmax over j. lane holds rows i_loc = (lane>>4)*4 + r, col j = jt*16 + (lane&15)
  const float scale = 0.125f;   // 1/sqrt(64)
  float rinv[4];
  #pragma unroll
  for (int r = 0; r < 4; ++r) {
    float m = S[0][r] * scale;
    #pragma unroll
    for (int jt = 1; jt < 4; ++jt) m = fmaxf(m, S[jt][r] * scale);
    #pragma unroll
    for (int off = 1; off < 16; off <<= 1) m = fmaxf(m, __shfl_xor(m, off, 64));
    float s = 0.f;
    #pragma unroll
    for (int jt = 0; jt < 4; ++jt) {
      float e = __expf(S[jt][r] * scale - m);
      S[jt][r] = e;
      s += e;
    }
    #pragma unroll
    for (int off = 1; off < 16; off <<= 1) s += __shfl_xor(s, off, 64);
    rinv[r] = 1.0f / s;
  }

  // write P (bf16) to LDS
  #pragma unroll
  for (int jt = 0; jt < 4; ++jt)
    #pragma unroll
    for (int r = 0; r < 4; ++r)
      ps[(wid * 16 + ((lane >> 4) << 2) + r) * 72 + jt * 16 + (lane & 15)] = f2b(S[jt][r]);
  __syncthreads();

  // O = P @ v   (K = 64 over j)
  f32x4 O[4] = {};
  {
    short8 pa[2];
    #pragma unroll
    for (int kk = 0; kk < 2; ++kk)
      pa[kk] = *(const short8*)(ps + (wid * 16 + (lane & 15)) * 72 + kk * 32 + ((lane >> 4) << 3));
    #pragma unroll
    for (int dt = 0; dt < 4; ++dt)
      #pragma unroll
      for (int kk = 0; kk < 2; ++kk) {
        short8 bv_ = *(const short8*)(vts + (dt * 16 + (lane & 15)) * 72 + kk * 32 + ((lane >> 4) << 3));
        O[dt] = __builtin_amdgcn_mfma_f32_16x16x32_bf16(pa[kk], bv_, O[dt], 0, 0, 0);
      }
  }

  // store fp32 output, rescaled by 1/rowsum
  #pragma unroll
  for (int dt = 0; dt < 4; ++dt)
    #pragma unroll
    for (int r = 0; r < 4; ++r)
      out[(s0 + wid * 16 + ((lane >> 4) << 2) + r) * DIM + h0 + dt * 16 + (lane & 15)] = O[dt][r] * rinv[r];
}

extern "C" void kernel_launch(void* const* d_in, const int* in_sizes, int n_in,
                              void* d_out, int out_size, void* d_ws, size_t ws_size,
                              hipStream_t stream) {
  const float* x  = (const float*)d_in[0];
  const float* Wq = (const float*)d_in[1];
  const float* bq = (const float*)d_in[2];
  const float* Wk = (const float*)d_in[3];
  const float* bk = (const float*)d_in[4];
  const float* Wv = (const float*)d_in[5];
  const float* bv = (const float*)d_in[6];
  float* out = (float*)d_out;

  char* ws = (char*)d_ws;
  u16* xb = (u16*)ws;                          // 32768*1024*2 = 67,108,864 B
  u16* wT = (u16*)(ws + 67108864);             // 3*1024*1024*2 = 6,291,456 B
  u16* qb = (u16*)(ws + 73400320);             // 67,108,864 B
  u16* kb = (u16*)(ws + 140509184);            // 67,108,864 B
  u16* vb = (u16*)(ws + 207618048);            // 67,108,864 B  (end 274,726,912)

  cvt_x_kernel<<<16384, 256, 0, stream>>>(x, xb, 4194304);
  cvt_wT_kernel<<<1536, 256, 0, stream>>>(Wq, Wk, Wv, wT);
  qkv_gemm_kernel<<<dim3(256, 24), 256, 0, stream>>>(xb, wT, bq, bk, bv, qb, kb, vb);
  blk_attn_kernel<<<8192, 256, 0, stream>>>(qb, kb, vb, out);
}

// Round 2
// 362.652 us; speedup vs baseline: 1.1406x; 1.1406x over previous
//
#include <hip/hip_runtime.h>
#include <hip/hip_bf16.h>

typedef __attribute__((ext_vector_type(8))) short short8;
typedef __attribute__((ext_vector_type(4))) float f32x4;
typedef unsigned short u16;

// Problem constants (B=4, S=8192, D=1024, H=16, d=64, bs=64)
#define M_TOK   32768
#define DIM     1024
#define NHEAD   16
#define HDIM    64
#define NBLK    128
#define NKT     32         // K / 32 tiles for the GEMM

__device__ __forceinline__ u16 f2b(float f) {
  union { float f; unsigned u; } v; v.f = f;
  unsigned r = (v.u + 0x7FFFu + ((v.u >> 16) & 1u)) >> 16;
  return (u16)r;
}

// ---------------- convert x fp32 -> bf16 ------------------------------------
__global__ void cvt_x_kernel(const float* __restrict__ in, u16* __restrict__ out, int n8) {
  int i = blockIdx.x * 256 + threadIdx.x;
  if (i >= n8) return;
  const float4* p = (const float4*)in + (size_t)i * 2;
  float4 a = p[0], c = p[1];
  short8 o;
  o[0] = (short)f2b(a.x); o[1] = (short)f2b(a.y); o[2] = (short)f2b(a.z); o[3] = (short)f2b(a.w);
  o[4] = (short)f2b(c.x); o[5] = (short)f2b(c.y); o[6] = (short)f2b(c.z); o[7] = (short)f2b(c.w);
  *((short8*)out + i) = o;
}

// ------------- convert W (K,N) fp32 -> W^T (N,K) bf16, 3 matrices -----------
__global__ void cvt_wT_kernel(const float* __restrict__ Wq, const float* __restrict__ Wk,
                              const float* __restrict__ Wv, u16* __restrict__ wT) {
  int t = blockIdx.x * 256 + threadIdx.x;
  int mat = t >> 17;
  int rem = t & 131071;
  int kg  = rem >> 10;
  int n   = rem & 1023;
  const float* W = (mat == 0) ? Wq : (mat == 1) ? Wk : Wv;
  short8 v;
  #pragma unroll
  for (int i = 0; i < 8; ++i) v[i] = (short)f2b(W[(size_t)(kg * 8 + i) * DIM + n]);
  *(short8*)(wT + ((size_t)mat << 20) + (size_t)n * DIM + kg * 8) = v;
}

// ---------------- QKV projection GEMM, 256x256 tile, 3-buffer ring ----------
// 512 threads = 8 waves (2M x 4N). Per-wave output 128x64 = acc[8][4] f32x4.
// BK=32. LDS buffer: [256 rows][A 32elem | B 32elem] = 128B rows, XOR-swizzled
// at 16B-slot granularity: phys_slot = logical_slot ^ (row & 7).
// Staging: linear global_load_lds dest + pre-swizzled per-lane global source.
// Ring discipline: compute tile t from buf[t%3]; stage tile t+2 into
// buf[(t+2)%3] (== buf[(t-1)%3], all waves finished it at the tile-t barrier).
// vmcnt(4) counted wait -> pipeline never drains in the main loop.
__global__ __launch_bounds__(512, 2) void qkv_gemm_kernel(
    const u16* __restrict__ xb, const u16* __restrict__ wT,
    const float* __restrict__ bq, const float* __restrict__ bk, const float* __restrict__ bv,
    u16* __restrict__ qb, u16* __restrict__ kb, u16* __restrict__ vb)
{
  __shared__ u16 lds[3][256 * 64];   // 3 x 32 KiB = 96 KiB

  const int tid  = threadIdx.x;
  const int lane = tid & 63;
  const int wid  = tid >> 6;

  // XCD-chunked bijective swizzle: 1536 blocks = 8 XCDs x 192
  const int orig = blockIdx.x;
  const int wg   = (orig & 7) * 192 + (orig >> 3);
  const int bm   = wg / 12;            // 0..127
  const int bn   = wg % 12;            // 0..11
  const int mat  = bn >> 2;            // 0=q 1=k 2=v
  const int col0 = (bn & 3) << 8;
  const int row0 = bm << 8;
  const u16* Wm = wT + ((size_t)mat << 20);
  const float* bias = (mat == 0) ? bq : (mat == 1) ? bk : bv;
  u16* outp = (mat == 0) ? qb : (mat == 1) ? kb : vb;

  const int wr = wid >> 2;             // 0..1  (M side)
  const int wc = wid & 3;              // 0..3  (N side)

  // ---- staging source (pre-swizzled): lane -> (row, phys slot lane&7) ------
  // logical slot l = (lane&7) ^ ((lane>>3)&7); l<4 -> A chunk l, else B chunk l-4
  const int l    = (lane & 7) ^ ((lane >> 3) & 7);
  const int rl0  = wid * 8 + (lane >> 3);          // row within 64-row chunk c
  const u16* gsrc0 = (l < 4)
      ? xb + (size_t)(row0 + rl0) * DIM + l * 8
      : Wm + (size_t)(col0 + rl0) * DIM + (l - 4) * 8;

  // ---- fragment read offsets (elements, swizzled) ---------------------------
  int aoff[8], boff[4];
  #pragma unroll
  for (int mi = 0; mi < 8; ++mi) {
    int r = wr * 128 + mi * 16 + (lane & 15);
    aoff[mi] = r * 64 + (((lane >> 4) ^ (r & 7)) << 3);
  }
  #pragma unroll
  for (int ni = 0; ni < 4; ++ni) {
    int r = wc * 64 + ni * 16 + (lane & 15);
    boff[ni] = r * 64 + (((4 + (lane >> 4)) ^ (r & 7)) << 3);
  }

  f32x4 acc[8][4] = {};

  // stage(kt) into buffer bi: 4 x global_load_lds, each 64 rows
  auto STAGE = [&](int kt, int bi) {
    const u16* s = gsrc0 + kt * 32;
    #pragma unroll
    for (int c = 0; c < 4; ++c) {
      __builtin_amdgcn_global_load_lds(
          (const __attribute__((address_space(1))) void*)(s + (size_t)c * 64 * DIM),
          (__attribute__((address_space(3))) void*)(&lds[bi][c * 4096 + wid * 512]),
          16, 0, 0);
    }
  };

  STAGE(0, 0);
  STAGE(1, 1);

  int cur = 0;                          // buf index of tile t
  for (int t = 0; t < NKT; ++t) {
    if (t + 1 < NKT) asm volatile("s_waitcnt vmcnt(4)" ::: "memory");
    else             asm volatile("s_waitcnt vmcnt(0)" ::: "memory");
    __builtin_amdgcn_s_barrier();
    if (t + 2 < NKT) {
      int nb = cur >= 1 ? cur - 1 : cur + 2;   // (t+2)%3 == (t-1)%3
      STAGE(t + 2, nb);
    }
    const u16* B = &lds[cur][0];
    short8 a[8], b[4];
    #pragma unroll
    for (int mi = 0; mi < 8; ++mi) a[mi] = *(const short8*)(B + aoff[mi]);
    #pragma unroll
    for (int ni = 0; ni < 4; ++ni) b[ni] = *(const short8*)(B + boff[ni]);
    __builtin_amdgcn_s_setprio(1);
    #pragma unroll
    for (int mi = 0; mi < 8; ++mi)
      #pragma unroll
      for (int ni = 0; ni < 4; ++ni)
        acc[mi][ni] = __builtin_amdgcn_mfma_f32_16x16x32_bf16(a[mi], b[ni], acc[mi][ni], 0, 0, 0);
    __builtin_amdgcn_s_setprio(0);
    cur = cur < 2 ? cur + 1 : 0;
  }

  // epilogue: bias + bf16 store. C/D layout: col = lane&15, row = (lane>>4)*4 + r
  #pragma unroll
  for (int ni = 0; ni < 4; ++ni) {
    int gcol = col0 + wc * 64 + ni * 16 + (lane & 15);
    float bb = bias[gcol];
    #pragma unroll
    for (int mi = 0; mi < 8; ++mi) {
      int grow = row0 + wr * 128 + mi * 16 + ((lane >> 4) << 2);
      #pragma unroll
      for (int r = 0; r < 4; ++r)
        outp[(size_t)(grow + r) * DIM + gcol] = f2b(acc[mi][ni][r] + bb);
    }
  }
}

// ---------------- block-diagonal attention: one WG per (b, blk, h) -----------
__global__ __launch_bounds__(256) void blk_attn_kernel(
    const u16* __restrict__ qb, const u16* __restrict__ kb, const u16* __restrict__ vb,
    float* __restrict__ out)
{
  __shared__ u16 qs[64 * 72];
  __shared__ u16 ks[64 * 72];
  __shared__ u16 vts[64 * 72];
  __shared__ u16 ps[64 * 72];

  const int tid  = threadIdx.x;
  const int lane = tid & 63;
  const int wid  = tid >> 6;
  const int idx  = blockIdx.x;
  const int h    = idx & 15;
  const int blk  = (idx >> 4) & 127;
  const int b    = idx >> 11;
  const size_t s0 = (size_t)b * 8192 + (size_t)blk * 64;
  const int h0 = h * HDIM;

  {
    int i  = tid >> 2;
    int cg = (tid & 3) * 16;
    const u16* qg = qb + (s0 + i) * DIM + h0 + cg;
    *(short8*)(qs + i * 72 + cg)     = *(const short8*)qg;
    *(short8*)(qs + i * 72 + cg + 8) = *(const short8*)(qg + 8);
    const u16* kg = kb + (s0 + i) * DIM + h0 + cg;
    *(short8*)(ks + i * 72 + cg)     = *(const short8*)kg;
    *(short8*)(ks + i * 72 + cg + 8) = *(const short8*)(kg + 8);
    const u16* vg = vb + (s0 + i) * DIM + h0 + cg;
    short8 v0 = *(const short8*)vg;
    short8 v1 = *(const short8*)(vg + 8);
    #pragma unroll
    for (int e = 0; e < 8; ++e) {
      vts[(cg + e) * 72 + i]     = (u16)v0[e];
      vts[(cg + 8 + e) * 72 + i] = (u16)v1[e];
    }
  }
  __syncthreads();

  f32x4 S[4] = {};
  {
    short8 aq[2];
    #pragma unroll
    for (int kk = 0; kk < 2; ++kk)
      aq[kk] = *(const short8*)(qs + (wid * 16 + (lane & 15)) * 72 + kk * 32 + ((lane >> 4) << 3));
    #pragma unroll
    for (int jt = 0; jt < 4; ++jt)
      #pragma unroll
      for (int kk = 0; kk < 2; ++kk) {
        short8 bk_ = *(const short8*)(ks + (jt * 16 + (lane & 15)) * 72 + kk * 32 + ((lane >> 4) << 3));
        S[jt] = __builtin_amdgcn_mfma_f32_16x16x32_bf16(aq[kk], bk_, S[jt], 0, 0, 0);
      }
  }

  const float scale = 0.125f;
  float rinv[4];
  #pragma unroll
  for (int r = 0; r < 4; ++r) {
    float m = S[0][r] * scale;
    #pragma unroll
    for (int jt = 1; jt < 4; ++jt) m = fmaxf(m, S[jt][r] * scale);
    #pragma unroll
    for (int off = 1; off < 16; off <<= 1) m = fmaxf(m, __shfl_xor(m, off, 64));
    float s = 0.f;
    #pragma unroll
    for (int jt = 0; jt < 4; ++jt) {
      float e = __expf(S[jt][r] * scale - m);
      S[jt][r] = e;
      s += e;
    }
    #pragma unroll
    for (int off = 1; off < 16; off <<= 1) s += __shfl_xor(s, off, 64);
    rinv[r] = 1.0f / s;
  }

  #pragma unroll
  for (int jt = 0; jt < 4; ++jt)
    #pragma unroll
    for (int r = 0; r < 4; ++r)
      ps[(wid * 16 + ((lane >> 4) << 2) + r) * 72 + jt * 16 + (lane & 15)] = f2b(S[jt][r]);
  __syncthreads();

  f32x4 O[4] = {};
  {
    short8 pa[2];
    #pragma unroll
    for (int kk = 0; kk < 2; ++kk)
      pa[kk] = *(const short8*)(ps + (wid * 16 + (lane & 15)) * 72 + kk * 32 + ((lane >> 4) << 3));
    #pragma unroll
    for (int dt = 0; dt < 4; ++dt)
      #pragma unroll
      for (int kk = 0; kk < 2; ++kk) {
        short8 bv_ = *(const short8*)(vts + (dt * 16 + (lane & 15)) * 72 + kk * 32 + ((lane >> 4) << 3));
        O[dt] = __builtin_amdgcn_mfma_f32_16x16x32_bf16(pa[kk], bv_, O[dt], 0, 0, 0);
      }
  }

  #pragma unroll
  for (int dt = 0; dt < 4; ++dt)
    #pragma unroll
    for (int r = 0; r < 4; ++r)
      out[(s0 + wid * 16 + ((lane >> 4) << 2) + r) * DIM + h0 + dt * 16 + (lane & 15)] = O[dt][r] * rinv[r];
}

extern "C" void kernel_launch(void* const* d_in, const int* in_sizes, int n_in,
                              void* d_out, int out_size, void* d_ws, size_t ws_size,
                              hipStream_t stream) {
  const float* x  = (const float*)d_in[0];
  const float* Wq = (const float*)d_in[1];
  const float* bq = (const float*)d_in[2];
  const float* Wk = (const float*)d_in[3];
  const float* bk = (const float*)d_in[4];
  const float* Wv = (const float*)d_in[5];
  const float* bv = (const float*)d_in[6];
  float* out = (float*)d_out;

  char* ws = (char*)d_ws;
  u16* xb = (u16*)ws;                          // 67,108,864 B
  u16* wT = (u16*)(ws + 67108864);             // 6,291,456 B
  u16* qb = (u16*)(ws + 73400320);             // 67,108,864 B
  u16* kb = (u16*)(ws + 140509184);            // 67,108,864 B
  u16* vb = (u16*)(ws + 207618048);            // 67,108,864 B

  cvt_x_kernel<<<16384, 256, 0, stream>>>(x, xb, 4194304);
  cvt_wT_kernel<<<1536, 256, 0, stream>>>(Wq, Wk, Wv, wT);
  qkv_gemm_kernel<<<1536, 512, 0, stream>>>(xb, wT, bq, bk, bv, qb, kb, vb);
  blk_attn_kernel<<<8192, 256, 0, stream>>>(qb, kb, vb, out);
}

// Round 3
// 345.036 us; speedup vs baseline: 1.1989x; 1.0511x over previous
//
#include <hip/hip_runtime.h>
#include <hip/hip_bf16.h>

typedef __attribute__((ext_vector_type(8))) short short8;
typedef __attribute__((ext_vector_type(4))) float f32x4;
typedef unsigned short u16;

#define DIM     1024
#define NHEAD   16
#define HDIM    64
#define AS1 __attribute__((address_space(1)))
#define AS3 __attribute__((address_space(3)))

__device__ __forceinline__ u16 f2b(float f) {
  union { float f; unsigned u; } v; v.f = f;
  unsigned r = (v.u + 0x7FFFu + ((v.u >> 16) & 1u)) >> 16;
  return (u16)r;
}

// ---------------- convert x fp32 -> bf16 ------------------------------------
__global__ void cvt_x_kernel(const float* __restrict__ in, u16* __restrict__ out, int n8) {
  int i = blockIdx.x * 256 + threadIdx.x;
  if (i >= n8) return;
  const float4* p = (const float4*)in + (size_t)i * 2;
  float4 a = p[0], c = p[1];
  short8 o;
  o[0] = (short)f2b(a.x); o[1] = (short)f2b(a.y); o[2] = (short)f2b(a.z); o[3] = (short)f2b(a.w);
  o[4] = (short)f2b(c.x); o[5] = (short)f2b(c.y); o[6] = (short)f2b(c.z); o[7] = (short)f2b(c.w);
  *((short8*)out + i) = o;
}

// ------------- convert W (K,N) fp32 -> W^T (N,K) bf16, 3 matrices -----------
__global__ void cvt_wT_kernel(const float* __restrict__ Wq, const float* __restrict__ Wk,
                              const float* __restrict__ Wv, u16* __restrict__ wT) {
  int t = blockIdx.x * 256 + threadIdx.x;
  int mat = t >> 17;
  int rem = t & 131071;
  int kg  = rem >> 10;
  int n   = rem & 1023;
  const float* W = (mat == 0) ? Wq : (mat == 1) ? Wk : Wv;
  short8 v;
  #pragma unroll
  for (int i = 0; i < 8; ++i) v[i] = (short)f2b(W[(size_t)(kg * 8 + i) * DIM + n]);
  *(short8*)(wT + ((size_t)mat << 20) + (size_t)n * DIM + kg * 8) = v;
}

// ---------------- QKV GEMM: 256x256 tile, BK=64, 8-phase schedule -----------
// 512 thr = 8 waves (2M x 4N), per-wave 128x64 out (acc[8][4] f32x4).
// LDS: 2 dbuf x { A[256][64] | B[256][64] } bf16 = 128 KiB. Even K-tiles ->
// dbuf0, odd -> dbuf1. 16B-slot XOR swizzle phys = logical ^ (row&7):
// staged via linear LDS dest + pre-swizzled per-lane global src (rule #21),
// ds_read spreads 16 rows over 8 slots -> 2-way bank alias (free, m136).
// Per K-tile 4 phases: {ds_read | stage | bar | lgkmcnt(0) | 16 MFMA | bar}.
// Stage placement (iter t, kt=2t): p1:kt+1.B0 p2:kt+1.B1 p4:kt+2.A0
// p5:kt+2.A1 p6:kt+2.B0 p7:kt+2.B1 p8:kt+3.A0+A1 — each target's last read
// completed >=1 barrier before the stage issues => race-free by construction.
// Counted waits: vmcnt(2) end-p4, vmcnt(4) end-p8; never 0 in steady state.
#define STAGE(matB, h, ktile) do { \
  const u16* _s = (matB) ? srcB : srcA; \
  _Pragma("unroll") \
  for (int _j = 0; _j < 2; ++_j) { \
    int _c = _j * 8 + wid; \
    __builtin_amdgcn_global_load_lds( \
      (const AS1 void*)(_s + (size_t)((h) * 128 + _c * 8) * DIM + (ktile) * 64), \
      (AS3 void*)(lds + ((((ktile) & 1) << 15) + ((matB) << 14) + ((h) << 13) + _c * 512)), \
      16, 0, 0); \
  } \
} while (0)

#define LDA(d, g) do { \
  _Pragma("unroll") \
  for (int _mi = 0; _mi < 4; ++_mi) { \
    int _r = abase + ((g) * 4 + _mi) * 1024 + ((d) << 15); \
    a[_mi * 2]     = *(const short8*)(lds + _r + sx0); \
    a[_mi * 2 + 1] = *(const short8*)(lds + _r + sx1); \
  } \
} while (0)

#define LDB(d, dst, nB) do { \
  _Pragma("unroll") \
  for (int _ni = 0; _ni < 2; ++_ni) { \
    int _r = bbase + ((nB) + _ni) * 1024 + ((d) << 15) + 16384; \
    dst[_ni * 2]     = *(const short8*)(lds + _r + sx0); \
    dst[_ni * 2 + 1] = *(const short8*)(lds + _r + sx1); \
  } \
} while (0)

#define MF(g, nB, bset) do { \
  _Pragma("unroll") \
  for (int _mi = 0; _mi < 4; ++_mi) \
    _Pragma("unroll") \
    for (int _ni = 0; _ni < 2; ++_ni) \
      _Pragma("unroll") \
      for (int _kk = 0; _kk < 2; ++_kk) \
        acc[(g) * 4 + _mi][(nB) + _ni] = __builtin_amdgcn_mfma_f32_16x16x32_bf16( \
            a[_mi * 2 + _kk], bset[_ni * 2 + _kk], acc[(g) * 4 + _mi][(nB) + _ni], 0, 0, 0); \
} while (0)

#define PH_MID() do { \
  __builtin_amdgcn_s_barrier(); \
  asm volatile("s_waitcnt lgkmcnt(0)" ::: "memory"); \
  __builtin_amdgcn_sched_barrier(0); \
  __builtin_amdgcn_s_setprio(1); \
} while (0)

#define PH_END() do { \
  __builtin_amdgcn_s_setprio(0); \
  __builtin_amdgcn_s_barrier(); \
} while (0)

#define PH_END_VM(n) do { \
  __builtin_amdgcn_s_setprio(0); \
  asm volatile("s_waitcnt vmcnt(" #n ")" ::: "memory"); \
  __builtin_amdgcn_s_barrier(); \
} while (0)

__global__ __launch_bounds__(512, 2) void qkv_gemm_kernel(
    const u16* __restrict__ xb, const u16* __restrict__ wT,
    const float* __restrict__ bq, const float* __restrict__ bk, const float* __restrict__ bv,
    u16* __restrict__ qb, u16* __restrict__ kb, u16* __restrict__ vb)
{
  __shared__ u16 lds[65536];   // 128 KiB

  const int tid  = threadIdx.x;
  const int lane = tid & 63;
  const int wid  = tid >> 6;

  // XCD-chunked bijective swizzle: 1536 = 8 XCDs x 192
  const int orig = blockIdx.x;
  const int wg   = (orig & 7) * 192 + (orig >> 3);
  const int bm   = wg / 12;
  const int bn   = wg % 12;
  const int mat  = bn >> 2;
  const int col0 = (bn & 3) << 8;
  const int row0 = bm << 8;
  const u16* Wm = wT + ((size_t)mat << 20);
  const float* bias = (mat == 0) ? bq : (mat == 1) ? bk : bv;
  u16* outp = (mat == 0) ? qb : (mat == 1) ? kb : vb;

  const int wr = wid >> 2;             // 0..1
  const int wc = wid & 3;              // 0..3
  const int l15 = lane & 15, lhi = lane >> 4;

  // staging source (pre-swizzled so LDS dest stays linear)
  const int sr = lane >> 3;            // 0..7
  const int sl = (lane & 7) ^ sr;      // logical 16B slot
  const u16* srcA = xb + (size_t)(row0 + sr) * DIM + sl * 8;
  const u16* srcB = Wm + (size_t)(col0 + sr) * DIM + sl * 8;

  // fragment phys-slot offsets (elems): phys = logical ^ (row&7)
  const int sx0 = (lhi ^ (l15 & 7)) << 3;
  const int sx1 = ((4 + lhi) ^ (l15 & 7)) << 3;
  const int abase = (wr * 128 + l15) * 64;
  const int bbase = (wc * 64 + l15) * 64;

  f32x4 acc[8][4] = {};
  short8 a[8], b01[4], b23[4];

  // prologue: kt0 fully + kt1 A halves; counted wait leaves kt1.A in flight
  STAGE(0, 0, 0); STAGE(0, 1, 0); STAGE(1, 0, 0); STAGE(1, 1, 0);
  STAGE(0, 0, 1); STAGE(0, 1, 1);
  asm volatile("s_waitcnt vmcnt(4)" ::: "memory");
  __builtin_amdgcn_s_barrier();

  #pragma unroll 1
  for (int t = 0; t < 8; ++t) {
    const int kt = 2 * t;
    const bool pf = (t < 7);
    // ---- K-tile kt (dbuf0) ----
    // p1
    LDA(0, 0); LDB(0, b01, 0);
    STAGE(1, 0, kt + 1);
    asm volatile("s_waitcnt lgkmcnt(8)" ::: "memory");
    PH_MID(); MF(0, 0, b01); PH_END();
    // p2
    LDB(0, b23, 2);
    STAGE(1, 1, kt + 1);
    PH_MID(); MF(0, 2, b23); PH_END();
    // p3
    LDA(0, 1);
    PH_MID(); MF(1, 2, b23); PH_END();
    // p4 (b01 still live in regs)
    if (pf) STAGE(0, 0, kt + 2);
    PH_MID(); MF(1, 0, b01);
    if (pf) { PH_END_VM(2); } else { PH_END_VM(0); }
    // ---- K-tile kt+1 (dbuf1) ----
    // p5
    LDA(1, 0); LDB(1, b01, 0);
    if (pf) STAGE(0, 1, kt + 2);
    asm volatile("s_waitcnt lgkmcnt(8)" ::: "memory");
    PH_MID(); MF(0, 0, b01); PH_END();
    // p6
    LDB(1, b23, 2);
    if (pf) STAGE(1, 0, kt + 2);
    PH_MID(); MF(0, 2, b23); PH_END();
    // p7
    LDA(1, 1);
    if (pf) STAGE(1, 1, kt + 2);
    PH_MID(); MF(1, 2, b23); PH_END();
    // p8
    if (pf) { STAGE(0, 0, kt + 3); STAGE(0, 1, kt + 3); }
    PH_MID(); MF(1, 0, b01);
    if (pf) { PH_END_VM(4); } else { PH_END_VM(0); }
  }

  // epilogue: bias + bf16 store. C/D: col = l15, row = lhi*4 + r
  #pragma unroll
  for (int ni = 0; ni < 4; ++ni) {
    int gcol = col0 + wc * 64 + ni * 16 + l15;
    float bb = bias[gcol];
    #pragma unroll
    for (int mi = 0; mi < 8; ++mi) {
      int grow = row0 + wr * 128 + mi * 16 + (lhi << 2);
      #pragma unroll
      for (int r = 0; r < 4; ++r)
        outp[(size_t)(grow + r) * DIM + gcol] = f2b(acc[mi][ni][r] + bb);
    }
  }
}

// ---------------- block-diagonal attention: one WG per (b, blk, h) -----------
__global__ __launch_bounds__(256) void blk_attn_kernel(
    const u16* __restrict__ qb, const u16* __restrict__ kb, const u16* __restrict__ vb,
    float* __restrict__ out)
{
  __shared__ u16 qs[64 * 72];
  __shared__ u16 ks[64 * 72];
  __shared__ u16 vts[64 * 72];
  __shared__ u16 ps[64 * 72];

  const int tid  = threadIdx.x;
  const int lane = tid & 63;
  const int wid  = tid >> 6;
  const int idx  = blockIdx.x;
  const int h    = idx & 15;
  const int blk  = (idx >> 4) & 127;
  const int b    = idx >> 11;
  const size_t s0 = (size_t)b * 8192 + (size_t)blk * 64;
  const int h0 = h * HDIM;

  {
    int i  = tid >> 2;
    int cg = (tid & 3) * 16;
    const u16* qg = qb + (s0 + i) * DIM + h0 + cg;
    *(short8*)(qs + i * 72 + cg)     = *(const short8*)qg;
    *(short8*)(qs + i * 72 + cg + 8) = *(const short8*)(qg + 8);
    const u16* kg = kb + (s0 + i) * DIM + h0 + cg;
    *(short8*)(ks + i * 72 + cg)     = *(const short8*)kg;
    *(short8*)(ks + i * 72 + cg + 8) = *(const short8*)(kg + 8);
    const u16* vg = vb + (s0 + i) * DIM + h0 + cg;
    short8 v0 = *(const short8*)vg;
    short8 v1 = *(const short8*)(vg + 8);
    #pragma unroll
    for (int e = 0; e < 8; ++e) {
      vts[(cg + e) * 72 + i]     = (u16)v0[e];
      vts[(cg + 8 + e) * 72 + i] = (u16)v1[e];
    }
  }
  __syncthreads();

  f32x4 S[4] = {};
  {
    short8 aq[2];
    #pragma unroll
    for (int kk = 0; kk < 2; ++kk)
      aq[kk] = *(const short8*)(qs + (wid * 16 + (lane & 15)) * 72 + kk * 32 + ((lane >> 4) << 3));
    #pragma unroll
    for (int jt = 0; jt < 4; ++jt)
      #pragma unroll
      for (int kk = 0; kk < 2; ++kk) {
        short8 bk_ = *(const short8*)(ks + (jt * 16 + (lane & 15)) * 72 + kk * 32 + ((lane >> 4) << 3));
        S[jt] = __builtin_amdgcn_mfma_f32_16x16x32_bf16(aq[kk], bk_, S[jt], 0, 0, 0);
      }
  }

  const float scale = 0.125f;
  float rinv[4];
  #pragma unroll
  for (int r = 0; r < 4; ++r) {
    float m = S[0][r] * scale;
    #pragma unroll
    for (int jt = 1; jt < 4; ++jt) m = fmaxf(m, S[jt][r] * scale);
    #pragma unroll
    for (int off = 1; off < 16; off <<= 1) m = fmaxf(m, __shfl_xor(m, off, 64));
    float s = 0.f;
    #pragma unroll
    for (int jt = 0; jt < 4; ++jt) {
      float e = __expf(S[jt][r] * scale - m);
      S[jt][r] = e;
      s += e;
    }
    #pragma unroll
    for (int off = 1; off < 16; off <<= 1) s += __shfl_xor(s, off, 64);
    rinv[r] = 1.0f / s;
  }

  #pragma unroll
  for (int jt = 0; jt < 4; ++jt)
    #pragma unroll
    for (int r = 0; r < 4; ++r)
      ps[(wid * 16 + ((lane >> 4) << 2) + r) * 72 + jt * 16 + (lane & 15)] = f2b(S[jt][r]);
  __syncthreads();

  f32x4 O[4] = {};
  {
    short8 pa[2];
    #pragma unroll
    for (int kk = 0; kk < 2; ++kk)
      pa[kk] = *(const short8*)(ps + (wid * 16 + (lane & 15)) * 72 + kk * 32 + ((lane >> 4) << 3));
    #pragma unroll
    for (int dt = 0; dt < 4; ++dt)
      #pragma unroll
      for (int kk = 0; kk < 2; ++kk) {
        short8 bv_ = *(const short8*)(vts + (dt * 16 + (lane & 15)) * 72 + kk * 32 + ((lane >> 4) << 3));
        O[dt] = __builtin_amdgcn_mfma_f32_16x16x32_bf16(pa[kk], bv_, O[dt], 0, 0, 0);
      }
  }

  #pragma unroll
  for (int dt = 0; dt < 4; ++dt)
    #pragma unroll
    for (int r = 0; r < 4; ++r)
      out[(s0 + wid * 16 + ((lane >> 4) << 2) + r) * DIM + h0 + dt * 16 + (lane & 15)] = O[dt][r] * rinv[r];
}

extern "C" void kernel_launch(void* const* d_in, const int* in_sizes, int n_in,
                              void* d_out, int out_size, void* d_ws, size_t ws_size,
                              hipStream_t stream) {
  const float* x  = (const float*)d_in[0];
  const float* Wq = (const float*)d_in[1];
  const float* bq = (const float*)d_in[2];
  const float* Wk = (const float*)d_in[3];
  const float* bk = (const float*)d_in[4];
  const float* Wv = (const float*)d_in[5];
  const float* bv = (const float*)d_in[6];
  float* out = (float*)d_out;

  char* ws = (char*)d_ws;
  u16* xb = (u16*)ws;                          // 67,108,864 B
  u16* wT = (u16*)(ws + 67108864);             // 6,291,456 B
  u16* qb = (u16*)(ws + 73400320);             // 67,108,864 B
  u16* kb = (u16*)(ws + 140509184);            // 67,108,864 B
  u16* vb = (u16*)(ws + 207618048);            // 67,108,864 B

  cvt_x_kernel<<<16384, 256, 0, stream>>>(x, xb, 4194304);
  cvt_wT_kernel<<<1536, 256, 0, stream>>>(Wq, Wk, Wv, wT);
  qkv_gemm_kernel<<<1536, 512, 0, stream>>>(xb, wT, bq, bk, bv, qb, kb, vb);
  blk_attn_kernel<<<8192, 256, 0, stream>>>(qb, kb, vb, out);
}